// Round 4
// baseline (133.457 us; speedup 1.0000x reference)
//
#include <hip/hip_runtime.h>
#include <math.h>

#define EPSF 1e-8f

typedef _Float16 f16x8 __attribute__((ext_vector_type(8)));
typedef float    f32x4 __attribute__((ext_vector_type(4)));

constexpr int Bb = 8, Nn = 32768, Kk = 64, Dd = 64;

// GEMM-ified: C[k][n] = sum_d slots[k][d] * features[n][d] via
// v_mfma_f32_16x16x32_f16 with fp32 operands split hi/lo into f16
// (3 products: hi*hi + hi*lo + lo*hi ~ fp32-accurate).
//
// Round-4 revision. Evidence so far:
//   r2 (single tile, bounds(256,4)): 43.6us, VALUBusy 35, MfmaUtil 5.5,
//      occupancy 28% (~2.3 waves/SIMD), HBM clean, warm-cache just as slow.
//   r3 (fused 2 tiles, 2x MFMA ILP, 6x fewer epilogue LDS reads): ~42us.
//      => per-wave ILP is NOT the constraint. TLP is: residency ceiling
//      16 waves/CU at bounds(256,4), measured average only 9.
// This round: lean single-tile waves + __launch_bounds__(256,5) -> unified
// reg cap 102 (hand count ~75-85 incl. AGPR acc), residency ceiling
// 20 waves/CU. 4096 blocks (16/CU over 5 resident = 3.2 generations).
// No software prefetch: latency hiding comes from waves, not unrolling.
// Spill tripwire: FETCH/WRITE must stay ~33/65.5 MB (round-1 lesson).
__global__ __launch_bounds__(256, 5) void attn_kernel(
    const float* __restrict__ features,
    const float* __restrict__ slots,
    const float* __restrict__ horizons,
    float* __restrict__ out)
{
    __shared__ float4 s_kp[Kk];      // (st, ss2_spatial, 1/(h+eps), pad)
    __shared__ f16x8 s_ahi[8][64];   // [t*2+c][lane] 8KB
    __shared__ f16x8 s_alo[8][64];   // 8KB

    const int tid  = threadIdx.x;
    const int bid  = blockIdx.x;
    const int b    = bid >> 9;        // 512 blocks per batch
    const int blk  = bid & 511;
    const int lane = tid & 63;
    const int wid  = tid >> 6;
    const int m    = lane & 15;       // MFMA row/col lane index
    const int quad = lane >> 4;

    // ---- per-block slot constants, packed; unroll 4 caps reg spike ----
    if (tid < Kk) {
        const float4* sr = (const float4*)(slots + (size_t)(b * Kk + tid) * Dd);
        float st = 0.f, ss = 0.f;
        #pragma unroll 4
        for (int i = 0; i < 16; ++i) {
            float4 u = sr[i];
            if (i == 0) st = u.x;
            ss += u.x * u.x + u.y * u.y + u.z * u.z + u.w * u.w;
        }
        ss -= st * st;               // exclude time dim d0
        s_kp[tid] = make_float4(st, ss, 1.0f / (horizons[b * Kk + tid] + EPSF), 0.f);
    }

    // ---- cooperative A staging: thread (t=wid, lane) splits 2 fragments ----
    {
        const int t = wid;
        #pragma unroll
        for (int c = 0; c < 2; ++c) {
            const float* sp = slots + (size_t)(b * Kk + 16 * t + m) * Dd
                            + 32 * c + quad * 8;
            float4 u0 = *(const float4*)sp;
            float4 u1 = *(const float4*)(sp + 4);
            float fv[8] = {u0.x, u0.y, u0.z, u0.w, u1.x, u1.y, u1.z, u1.w};
            if (c == 0 && quad == 0) fv[0] = 0.0f;     // time dim out of dot
            f16x8 h8, l8;
            #pragma unroll
            for (int j = 0; j < 8; ++j) {
                float x = fv[j];
                _Float16 h = (_Float16)x;              // RN split
                _Float16 l = (_Float16)(x - (float)h);
                h8[j] = h;
                l8[j] = l;
            }
            s_ahi[t * 2 + c][lane] = h8;
            s_alo[t * 2 + c][lane] = l8;
        }
    }
    __syncthreads();

    const int n0 = (blk * 4 + wid) * 16;   // one 16-n tile per wave

    // ---- tile load: 4 dwordx4 per lane ----
    float4 buf[4];
    {
        const float* fp = features + (((size_t)b << 15) + n0 + m) * Dd + quad * 8;
        buf[0] = *(const float4*)(fp);
        buf[1] = *(const float4*)(fp + 4);
        buf[2] = *(const float4*)(fp + 32);
        buf[3] = *(const float4*)(fp + 36);
    }

    // ---- split into f16 hi/lo fragments + fs2 ----
    f16x8 bh[2], bl[2];
    const float f00 = buf[0].x;            // quad==0 lanes hold f[n][0]
    float fs2 = 0.f;
    #pragma unroll
    for (int c = 0; c < 2; ++c) {
        float4 u0 = buf[2 * c];
        float4 u1 = buf[2 * c + 1];
        float fv[8] = {u0.x, u0.y, u0.z, u0.w, u1.x, u1.y, u1.z, u1.w};
        #pragma unroll
        for (int j = 0; j < 8; ++j) {
            float x = fv[j];
            fs2 = fmaf(x, x, fs2);
            _Float16 h = (_Float16)x;
            _Float16 l = (_Float16)(x - (float)h);
            bh[c][j] = h;
            bl[c][j] = l;
        }
    }
    const float ft = __shfl(f00, m);       // lane m (<16, quad 0)
    fs2 += __shfl_xor(fs2, 16);
    fs2 += __shfl_xor(fs2, 32);            // full |f|^2 over 64 d
    fs2 = fmaf(-ft, ft, fs2);              // spatial only

    // ---- 24 MFMAs: 4 independent 6-chains (one per k-row-tile t) ----
    f32x4 acc[4];
    #pragma unroll
    for (int t = 0; t < 4; ++t) {
        f16x8 ah0 = s_ahi[t * 2 + 0][lane];
        f16x8 ah1 = s_ahi[t * 2 + 1][lane];
        f16x8 al0 = s_alo[t * 2 + 0][lane];
        f16x8 al1 = s_alo[t * 2 + 1][lane];
        f32x4 a = {0.f, 0.f, 0.f, 0.f};
        a = __builtin_amdgcn_mfma_f32_16x16x32_f16(ah0, bh[0], a, 0, 0, 0);
        a = __builtin_amdgcn_mfma_f32_16x16x32_f16(ah0, bl[0], a, 0, 0, 0);
        a = __builtin_amdgcn_mfma_f32_16x16x32_f16(al0, bh[0], a, 0, 0, 0);
        a = __builtin_amdgcn_mfma_f32_16x16x32_f16(ah1, bh[1], a, 0, 0, 0);
        a = __builtin_amdgcn_mfma_f32_16x16x32_f16(ah1, bl[1], a, 0, 0, 0);
        a = __builtin_amdgcn_mfma_f32_16x16x32_f16(al1, bh[1], a, 0, 0, 0);
        acc[t] = a;
    }

    // ---- epilogue: logits -> pe (overlaid into acc), running sum ----
    float sum = 0.f;
    #pragma unroll
    for (int t = 0; t < 4; ++t) {
        #pragma unroll
        for (int r = 0; r < 4; ++r) {
            const int k = 16 * t + quad * 4 + r;   // C row
            float4 kp = s_kp[k];                   // st, ss2, rh
            float cross = acc[t][r];               // spatial dot
            float dt  = ft - kp.x;
            float dx2 = fmaf(-2.f, cross, fs2 + kp.y);
            dx2 = fmaxf(dx2, 0.f);
            float interval = fmaf(dt, dt, -dx2);
            float adist = __builtin_amdgcn_sqrtf(fabsf(interval) + EPSF);
            float cone  = (fabsf(dt) - __builtin_amdgcn_sqrtf(dx2 + EPSF)) * kp.z;
            float e  = __expf(2.0f * cone);        // tanh via exp, NaN-free
            float th = 1.0f - 2.0f * __builtin_amdgcn_rcpf(e + 1.0f);
            float logit = fmaf(0.5f, th, -adist);  // <= +0.5: exp safe
            float pe = __expf(logit);
            acc[t][r] = pe;                        // overlay: acc reused as p
            sum += pe;
        }
    }
    sum += __shfl_xor(sum, 16);
    sum += __shfl_xor(sum, 32);                    // total over 64 k
    const float inv = __builtin_amdgcn_rcpf(sum);

    // ---- stores: per (t,r) instr writes 4 k-rows x 64B contiguous ----
    float* ob = out + (((size_t)(b * Kk)) << 15) + n0 + m;
    #pragma unroll
    for (int t = 0; t < 4; ++t) {
        #pragma unroll
        for (int r = 0; r < 4; ++r) {
            const int k = 16 * t + quad * 4 + r;
            ob[(size_t)k << 15] = acc[t][r] * inv;
        }
    }
}

extern "C" void kernel_launch(void* const* d_in, const int* in_sizes, int n_in,
                              void* d_out, int out_size, void* d_ws, size_t ws_size,
                              hipStream_t stream) {
    const float* features = (const float*)d_in[0];
    const float* slots    = (const float*)d_in[1];
    const float* horizons = (const float*)d_in[2];
    float* out = (float*)d_out;

    // 4096 blocks x 256 thr = 16384 waves; each wave: 1 tile of 16 n.
    hipLaunchKernelGGL(attn_kernel, dim3(4096), dim3(256), 0, stream,
                       features, slots, horizons, out);
}

// Round 5
// 124.508 us; speedup vs baseline: 1.0719x; 1.0719x over previous
//
#include <hip/hip_runtime.h>
#include <math.h>

#define EPSF 1e-8f

typedef _Float16 f16x8 __attribute__((ext_vector_type(8)));
typedef float    f32x4 __attribute__((ext_vector_type(4)));

constexpr int Bb = 8, Nn = 32768, Kk = 64, Dd = 64;

// GEMM-ified: C[k][n] = sum_d slots[k][d] * features[n][d] via
// v_mfma_f32_16x16x32_f16 with fp32 operands split hi/lo into f16
// (3 products: hi*hi + hi*lo + lo*hi ~ fp32-accurate).
//
// Round-5 revision. Evidence ledger:
//   r2 (2 tiles/wave, unroll+prefetch = 2-tile ILP, 9 waves/CU): 43.6us
//   r3 (explicit 2-tile fuse): ~42us  -> r2 was already 2-ILP; neutral
//   r4 (1 tile/wave, 12 waves/CU):    47.4us -> fewer concurrent tiles
//   => binding constraint = concurrent tiles/CU (waves x tiles/wave).
//      Achieved waves/CU pinned ~9-12 regardless of launch_bounds ceiling;
//      nothing issue-saturated (VALU 16us busy of 43.6; trans ~10%;
//      memory floor ~15us). So push ILP: 4 fused tiles/wave.
//  * all 16 feature dwordx4 issued up front (16KB/wave in flight)
//  * per-t A-frag LDS read shared by 4 tiles' MFMA chains (4 reads/tile,
//    was 16) -- 16 independent 6-chains total
//  * 4-way interleaved epilogue: 64 independent trans chains per lane
//  * stores: 4 tiles x 16 k-rows, 64B each, n-contiguous per k-row
//  * launch_bounds(256,3): unified cap ~168 vs peak ~155 (frags 64 +
//    acc 64 + A 16 + misc). Spill tripwire: FETCH/WRITE must stay
//    ~33/65.5 MB (round-1 lesson: spill = +110MB = +40us).
__global__ __launch_bounds__(256, 3) void attn_kernel(
    const float* __restrict__ features,
    const float* __restrict__ slots,
    const float* __restrict__ horizons,
    float* __restrict__ out)
{
    __shared__ float4 s_kp[Kk];      // (st, ss2_spatial, 1/(h+eps), pad)
    __shared__ f16x8 s_ahi[8][64];   // [t*2+c][lane] 8KB
    __shared__ f16x8 s_alo[8][64];   // 8KB

    const int tid  = threadIdx.x;
    const int bid  = blockIdx.x;
    const int b    = bid >> 7;        // 128 blocks per batch
    const int blk  = bid & 127;
    const int lane = tid & 63;
    const int wid  = tid >> 6;
    const int m    = lane & 15;       // MFMA row/col lane index
    const int quad = lane >> 4;

    // ---- per-block slot constants, packed; unroll 4 caps reg spike ----
    if (tid < Kk) {
        const float4* sr = (const float4*)(slots + (size_t)(b * Kk + tid) * Dd);
        float st = 0.f, ss = 0.f;
        #pragma unroll 4
        for (int i = 0; i < 16; ++i) {
            float4 u = sr[i];
            if (i == 0) st = u.x;
            ss += u.x * u.x + u.y * u.y + u.z * u.z + u.w * u.w;
        }
        ss -= st * st;               // exclude time dim d0
        s_kp[tid] = make_float4(st, ss, 1.0f / (horizons[b * Kk + tid] + EPSF), 0.f);
    }

    // ---- cooperative A staging: thread (t=wid, lane) splits 2 fragments ----
    {
        const int t = wid;
        #pragma unroll
        for (int c = 0; c < 2; ++c) {
            const float* sp = slots + (size_t)(b * Kk + 16 * t + m) * Dd
                            + 32 * c + quad * 8;
            float4 u0 = *(const float4*)sp;
            float4 u1 = *(const float4*)(sp + 4);
            float fv[8] = {u0.x, u0.y, u0.z, u0.w, u1.x, u1.y, u1.z, u1.w};
            if (c == 0 && quad == 0) fv[0] = 0.0f;     // time dim out of dot
            f16x8 h8, l8;
            #pragma unroll
            for (int j = 0; j < 8; ++j) {
                float x = fv[j];
                _Float16 h = (_Float16)x;              // RN split
                _Float16 l = (_Float16)(x - (float)h);
                h8[j] = h;
                l8[j] = l;
            }
            s_ahi[t * 2 + c][lane] = h8;
            s_alo[t * 2 + c][lane] = l8;
        }
    }
    __syncthreads();

    const int n0 = (blk * 16 + wid * 4) * 16;   // 4 consecutive 16-n tiles, fused

    // ---- all 4 tiles' loads issued up front: 16 dwordx4 in flight ----
    float4 buf[4][4];
    #pragma unroll
    for (int it = 0; it < 4; ++it) {
        const float* fp = features + (((size_t)b << 15) + n0 + it * 16 + m) * Dd
                        + quad * 8;
        buf[it][0] = *(const float4*)(fp);
        buf[it][1] = *(const float4*)(fp + 4);
        buf[it][2] = *(const float4*)(fp + 32);
        buf[it][3] = *(const float4*)(fp + 36);
    }

    // ---- split all 4 tiles into f16 hi/lo fragments + fs2 ----
    f16x8 bh[4][2], bl[4][2];
    float ft[4], fs2[4];
    #pragma unroll
    for (int it = 0; it < 4; ++it) {
        const float f00 = buf[it][0].x;        // quad==0 lanes hold f[n][0]
        float s = 0.f;
        #pragma unroll
        for (int c = 0; c < 2; ++c) {
            float4 u0 = buf[it][2 * c];
            float4 u1 = buf[it][2 * c + 1];
            float fv[8] = {u0.x, u0.y, u0.z, u0.w, u1.x, u1.y, u1.z, u1.w};
            #pragma unroll
            for (int j = 0; j < 8; ++j) {
                float x = fv[j];
                s = fmaf(x, x, s);
                _Float16 h = (_Float16)x;
                _Float16 l = (_Float16)(x - (float)h);
                bh[it][c][j] = h;
                bl[it][c][j] = l;
            }
        }
        float f = __shfl(f00, m);              // lane m (<16, quad 0)
        s += __shfl_xor(s, 16);
        s += __shfl_xor(s, 32);                // full |f|^2 over 64 d
        ft[it]  = f;
        fs2[it] = fmaf(-f, f, s);              // spatial only
    }

    // ---- 96 MFMAs: per A-read, 4 independent 6-chains (16 chains total) ----
    f32x4 acc[4][4];                           // [it][t]
    #pragma unroll
    for (int t = 0; t < 4; ++t) {
        f16x8 ah0 = s_ahi[t * 2 + 0][lane];
        f16x8 ah1 = s_ahi[t * 2 + 1][lane];
        f16x8 al0 = s_alo[t * 2 + 0][lane];
        f16x8 al1 = s_alo[t * 2 + 1][lane];
        #pragma unroll
        for (int it = 0; it < 4; ++it) {
            f32x4 a = {0.f, 0.f, 0.f, 0.f};
            a = __builtin_amdgcn_mfma_f32_16x16x32_f16(ah0, bh[it][0], a, 0, 0, 0);
            a = __builtin_amdgcn_mfma_f32_16x16x32_f16(ah0, bl[it][0], a, 0, 0, 0);
            a = __builtin_amdgcn_mfma_f32_16x16x32_f16(al0, bh[it][0], a, 0, 0, 0);
            a = __builtin_amdgcn_mfma_f32_16x16x32_f16(ah1, bh[it][1], a, 0, 0, 0);
            a = __builtin_amdgcn_mfma_f32_16x16x32_f16(ah1, bl[it][1], a, 0, 0, 0);
            a = __builtin_amdgcn_mfma_f32_16x16x32_f16(al1, bh[it][1], a, 0, 0, 0);
            acc[it][t] = a;
        }
    }

    // ---- epilogue: one packed kparam read serves all 4 tiles ----
    float sum[4] = {0.f, 0.f, 0.f, 0.f};
    #pragma unroll
    for (int t = 0; t < 4; ++t) {
        #pragma unroll
        for (int r = 0; r < 4; ++r) {
            const int k = 16 * t + quad * 4 + r;   // C row
            float4 kp = s_kp[k];                   // st, ss2, rh
            #pragma unroll
            for (int it = 0; it < 4; ++it) {       // 4 independent trans chains
                float cross = acc[it][t][r];
                float dt  = ft[it] - kp.x;
                float dx2 = fmaf(-2.f, cross, fs2[it] + kp.y);
                dx2 = fmaxf(dx2, 0.f);
                float interval = fmaf(dt, dt, -dx2);
                float adist = __builtin_amdgcn_sqrtf(fabsf(interval) + EPSF);
                float cone  = (fabsf(dt) - __builtin_amdgcn_sqrtf(dx2 + EPSF)) * kp.z;
                float e  = __expf(2.0f * cone);    // tanh via exp, NaN-free
                float th = 1.0f - 2.0f * __builtin_amdgcn_rcpf(e + 1.0f);
                float logit = fmaf(0.5f, th, -adist);  // <= +0.5: exp safe
                float pe = __expf(logit);
                acc[it][t][r] = pe;                // overlay: acc reused as p
                sum[it] += pe;
            }
        }
    }
    float inv[4];
    #pragma unroll
    for (int it = 0; it < 4; ++it) {
        float s = sum[it];
        s += __shfl_xor(s, 16);
        s += __shfl_xor(s, 32);                    // total over 64 k
        inv[it] = __builtin_amdgcn_rcpf(s);
    }

    // ---- stores: per k-row, 4 tiles x 16 lanes = 256B n-contiguous ----
    float* ob = out + (((size_t)(b * Kk)) << 15) + n0 + m;
    #pragma unroll
    for (int t = 0; t < 4; ++t) {
        #pragma unroll
        for (int r = 0; r < 4; ++r) {
            const int k = 16 * t + quad * 4 + r;
            #pragma unroll
            for (int it = 0; it < 4; ++it) {
                ob[((size_t)k << 15) + it * 16] = acc[it][t][r] * inv[it];
            }
        }
    }
}

extern "C" void kernel_launch(void* const* d_in, const int* in_sizes, int n_in,
                              void* d_out, int out_size, void* d_ws, size_t ws_size,
                              hipStream_t stream) {
    const float* features = (const float*)d_in[0];
    const float* slots    = (const float*)d_in[1];
    const float* horizons = (const float*)d_in[2];
    float* out = (float*)d_out;

    // 1024 blocks x 256 thr = 4096 waves; each wave: 4 fused tiles of 16 n.
    hipLaunchKernelGGL(attn_kernel, dim3(1024), dim3(256), 0, stream,
                       features, slots, horizons, out);
}

// Round 6
// 124.069 us; speedup vs baseline: 1.0757x; 1.0035x over previous
//
#include <hip/hip_runtime.h>
#include <math.h>

#define EPSF 1e-8f

typedef _Float16 f16x8 __attribute__((ext_vector_type(8)));
typedef float    f32x4 __attribute__((ext_vector_type(4)));

constexpr int Bb = 8, Nn = 32768, Kk = 64, Dd = 64;

// GEMM-ified: C[k][n] = sum_d slots[k][d] * features[n][d] via
// v_mfma_f32_16x16x32_f16 with fp32 operands split hi/lo into f16
// (3 products: hi*hi + hi*lo + lo*hi ~ fp32-accurate).
//
// Round-6 revision. Evidence ledger:
//   r0 60.8us | r2 43.6 | r3 ~42 | r4 47.4 | r5 41.4
//   Model fitting ALL rounds: T ~= sum(per-wave serial chains)/CU -- waves
//   provide ~no mutual latency hiding; the shared stall is the WRITE path:
//   * warm runs (FETCH~0, L3-served reads) are equally slow -> reads clean
//   * aggregate 2.4 TB/s vs fill kernel's 6.5 TB/s sequential
//   * output layout forces 256B segments at 8MB stride x ~200K streams
//     chip-wide -> DRAM page-activate bound; 65.5MB writes ~ 30us ~ floor.
// Change (one variable): block-cooperative LDS-staged stores.
//   Stage normalized out in LDS (2 phases x 32k x 256n, pad 260), flush
//   cooperatively: each global_store_dwordx4 writes 1KB CONTIGUOUS of one
//   k-row (64 store instrs/block, was 256; 4x burst size, tight timing).
//   Everything upstream of the store path is identical to r5.
__global__ __launch_bounds__(256, 3) void attn_kernel(
    const float* __restrict__ features,
    const float* __restrict__ slots,
    const float* __restrict__ horizons,
    float* __restrict__ out)
{
    __shared__ float4 s_kp[Kk];        // (st, ss2_spatial, 1/(h+eps), pad)
    __shared__ f16x8 s_ahi[8][64];     // [t*2+c][lane] 8KB
    __shared__ f16x8 s_alo[8][64];     // 8KB
    __shared__ float s_out[32][260];   // 32 k-rows x 256 n, pad->260 (33KB)

    const int tid  = threadIdx.x;
    const int bid  = blockIdx.x;
    const int b    = bid >> 7;        // 128 blocks per batch
    const int blk  = bid & 127;
    const int lane = tid & 63;
    const int wid  = tid >> 6;
    const int m    = lane & 15;       // MFMA row/col lane index
    const int quad = lane >> 4;

    // ---- per-block slot constants, packed; unroll 4 caps reg spike ----
    if (tid < Kk) {
        const float4* sr = (const float4*)(slots + (size_t)(b * Kk + tid) * Dd);
        float st = 0.f, ss = 0.f;
        #pragma unroll 4
        for (int i = 0; i < 16; ++i) {
            float4 u = sr[i];
            if (i == 0) st = u.x;
            ss += u.x * u.x + u.y * u.y + u.z * u.z + u.w * u.w;
        }
        ss -= st * st;               // exclude time dim d0
        s_kp[tid] = make_float4(st, ss, 1.0f / (horizons[b * Kk + tid] + EPSF), 0.f);
    }

    // ---- cooperative A staging: thread (t=wid, lane) splits 2 fragments ----
    {
        const int t = wid;
        #pragma unroll
        for (int c = 0; c < 2; ++c) {
            const float* sp = slots + (size_t)(b * Kk + 16 * t + m) * Dd
                            + 32 * c + quad * 8;
            float4 u0 = *(const float4*)sp;
            float4 u1 = *(const float4*)(sp + 4);
            float fv[8] = {u0.x, u0.y, u0.z, u0.w, u1.x, u1.y, u1.z, u1.w};
            if (c == 0 && quad == 0) fv[0] = 0.0f;     // time dim out of dot
            f16x8 h8, l8;
            #pragma unroll
            for (int j = 0; j < 8; ++j) {
                float x = fv[j];
                _Float16 h = (_Float16)x;              // RN split
                _Float16 l = (_Float16)(x - (float)h);
                h8[j] = h;
                l8[j] = l;
            }
            s_ahi[t * 2 + c][lane] = h8;
            s_alo[t * 2 + c][lane] = l8;
        }
    }
    __syncthreads();

    const int n0 = (blk * 16 + wid * 4) * 16;   // 4 consecutive 16-n tiles, fused

    // ---- all 4 tiles' loads issued up front: 16 dwordx4 in flight ----
    float4 buf[4][4];
    #pragma unroll
    for (int it = 0; it < 4; ++it) {
        const float* fp = features + (((size_t)b << 15) + n0 + it * 16 + m) * Dd
                        + quad * 8;
        buf[it][0] = *(const float4*)(fp);
        buf[it][1] = *(const float4*)(fp + 4);
        buf[it][2] = *(const float4*)(fp + 32);
        buf[it][3] = *(const float4*)(fp + 36);
    }

    // ---- split all 4 tiles into f16 hi/lo fragments + fs2 ----
    f16x8 bh[4][2], bl[4][2];
    float ft[4], fs2[4];
    #pragma unroll
    for (int it = 0; it < 4; ++it) {
        const float f00 = buf[it][0].x;        // quad==0 lanes hold f[n][0]
        float s = 0.f;
        #pragma unroll
        for (int c = 0; c < 2; ++c) {
            float4 u0 = buf[it][2 * c];
            float4 u1 = buf[it][2 * c + 1];
            float fv[8] = {u0.x, u0.y, u0.z, u0.w, u1.x, u1.y, u1.z, u1.w};
            #pragma unroll
            for (int j = 0; j < 8; ++j) {
                float x = fv[j];
                s = fmaf(x, x, s);
                _Float16 h = (_Float16)x;
                _Float16 l = (_Float16)(x - (float)h);
                bh[it][c][j] = h;
                bl[it][c][j] = l;
            }
        }
        float f = __shfl(f00, m);              // lane m (<16, quad 0)
        s += __shfl_xor(s, 16);
        s += __shfl_xor(s, 32);                // full |f|^2 over 64 d
        ft[it]  = f;
        fs2[it] = fmaf(-f, f, s);              // spatial only
    }

    // ---- 96 MFMAs: per A-read, 4 independent 6-chains (16 chains total) ----
    f32x4 acc[4][4];                           // [it][t]
    #pragma unroll
    for (int t = 0; t < 4; ++t) {
        f16x8 ah0 = s_ahi[t * 2 + 0][lane];
        f16x8 ah1 = s_ahi[t * 2 + 1][lane];
        f16x8 al0 = s_alo[t * 2 + 0][lane];
        f16x8 al1 = s_alo[t * 2 + 1][lane];
        #pragma unroll
        for (int it = 0; it < 4; ++it) {
            f32x4 a = {0.f, 0.f, 0.f, 0.f};
            a = __builtin_amdgcn_mfma_f32_16x16x32_f16(ah0, bh[it][0], a, 0, 0, 0);
            a = __builtin_amdgcn_mfma_f32_16x16x32_f16(ah0, bl[it][0], a, 0, 0, 0);
            a = __builtin_amdgcn_mfma_f32_16x16x32_f16(al0, bh[it][0], a, 0, 0, 0);
            a = __builtin_amdgcn_mfma_f32_16x16x32_f16(ah1, bh[it][1], a, 0, 0, 0);
            a = __builtin_amdgcn_mfma_f32_16x16x32_f16(ah1, bl[it][1], a, 0, 0, 0);
            a = __builtin_amdgcn_mfma_f32_16x16x32_f16(al1, bh[it][1], a, 0, 0, 0);
            acc[it][t] = a;
        }
    }

    // ---- epilogue: one packed kparam read serves all 4 tiles ----
    float sum[4] = {0.f, 0.f, 0.f, 0.f};
    #pragma unroll
    for (int t = 0; t < 4; ++t) {
        #pragma unroll
        for (int r = 0; r < 4; ++r) {
            const int k = 16 * t + quad * 4 + r;   // C row
            float4 kp = s_kp[k];                   // st, ss2, rh
            #pragma unroll
            for (int it = 0; it < 4; ++it) {       // 4 independent trans chains
                float cross = acc[it][t][r];
                float dt  = ft[it] - kp.x;
                float dx2 = fmaf(-2.f, cross, fs2[it] + kp.y);
                dx2 = fmaxf(dx2, 0.f);
                float interval = fmaf(dt, dt, -dx2);
                float adist = __builtin_amdgcn_sqrtf(fabsf(interval) + EPSF);
                float cone  = (fabsf(dt) - __builtin_amdgcn_sqrtf(dx2 + EPSF)) * kp.z;
                float e  = __expf(2.0f * cone);    // tanh via exp, NaN-free
                float th = 1.0f - 2.0f * __builtin_amdgcn_rcpf(e + 1.0f);
                float logit = fmaf(0.5f, th, -adist);  // <= +0.5: exp safe
                float pe = __expf(logit);
                acc[it][t][r] = pe;                // overlay: acc reused as p
                sum[it] += pe;
            }
        }
    }
    float inv[4];
    #pragma unroll
    for (int it = 0; it < 4; ++it) {
        float s = sum[it];
        s += __shfl_xor(s, 16);
        s += __shfl_xor(s, 32);                    // total over 64 k
        inv[it] = __builtin_amdgcn_rcpf(s);
    }

    // ---- stores: 2 phases; stage 32k x 256n in LDS, flush 1KB/instr ----
    const int nb = blk * 256;                      // block n-base
    #pragma unroll
    for (int ph = 0; ph < 2; ++ph) {
        // stage normalized outputs for k in [ph*32, ph*32+32)
        #pragma unroll
        for (int tt = 0; tt < 2; ++tt) {
            const int t  = ph * 2 + tt;
            #pragma unroll
            for (int r = 0; r < 4; ++r) {
                const int kr = 16 * tt + quad * 4 + r;   // row within phase
                #pragma unroll
                for (int it = 0; it < 4; ++it) {
                    s_out[kr][wid * 64 + it * 16 + m] = acc[it][t][r] * inv[it];
                }
            }
        }
        __syncthreads();
        // flush: wave wid stores rows wid*8 .. wid*8+7, 1KB contiguous each
        #pragma unroll
        for (int rr = 0; rr < 8; ++rr) {
            const int kr = wid * 8 + rr;
            const int k  = ph * 32 + kr;
            float4 v = *(const float4*)&s_out[kr][lane * 4];
            *(float4*)(out + (((size_t)(b * Kk + k)) << 15) + nb + lane * 4) = v;
        }
        __syncthreads();
    }
}

extern "C" void kernel_launch(void* const* d_in, const int* in_sizes, int n_in,
                              void* d_out, int out_size, void* d_ws, size_t ws_size,
                              hipStream_t stream) {
    const float* features = (const float*)d_in[0];
    const float* slots    = (const float*)d_in[1];
    const float* horizons = (const float*)d_in[2];
    float* out = (float*)d_out;

    // 1024 blocks x 256 thr = 4096 waves; each wave: 4 fused tiles of 16 n.
    // Block output: 64k x 256n, flushed as 64 x 1KB-contiguous stores.
    hipLaunchKernelGGL(attn_kernel, dim3(1024), dim3(256), 0, stream,
                       features, slots, horizons, out);
}